// Round 10
// baseline (1706.268 us; speedup 1.0000x reference)
//
#include <hip/hip_runtime.h>

typedef __attribute__((ext_vector_type(8))) short short8;
typedef __attribute__((ext_vector_type(4))) float f32x4;
typedef unsigned short u16;
typedef unsigned int u32;
typedef unsigned long long u64;

#define T_LEN 256
#define XSTEP_U16 32768      // x/y per-t: [kt:16][nt:4][512] u16 = 64KB
#define CHUNK_U16 512
#define GSLOT_U16 32768      // h-exchange per group per slot: 128 qw x 32 n x 8 u16

// workspace layout (bytes)
#define OFF_X0 0u
#define SZ_X0 (256u * 65536u)   // 16MB
#define OFF_Y0 (OFF_X0 + SZ_X0)
#define SZ_Y0 SZ_X0             // 16MB
#define OFF_HD (OFF_Y0 + SZ_Y0)
#define SZ_HD (4u * 2u * 65536u)  // 4 groups x 2 slots x 64KB = 512KB
#define OFF_POOL (OFF_HD + SZ_HD)
#define SZ_POOL (512u * 64u * 4u)
#define OFF_YFLG (OFF_POOL + SZ_POOL)
#define SZ_YFLG (2u * 32u * 4u)   // [sb][32 units] packed u32

__device__ __forceinline__ u16 f2bf(float x) {
  unsigned u = __builtin_bit_cast(unsigned, x);
  return (u16)((u + 0x7fffu + ((u >> 16) & 1u)) >> 16);
}
__device__ __forceinline__ float sigf(float x) { return 1.f / (1.f + __expf(-x)); }
__device__ __forceinline__ float tanhfast(float x) {
  float e = __expf(2.f * x);
  return 1.f - 2.f / (e + 1.f);
}

// sc1 (LLC-coherent) relaxed primitives
__device__ __forceinline__ u64 ld8_llc(const u64* p) {
  return __hip_atomic_load(p, __ATOMIC_RELAXED, __HIP_MEMORY_SCOPE_AGENT);
}
__device__ __forceinline__ void st8_llc(u64* p, u64 v) {
  __hip_atomic_store(p, v, __ATOMIC_RELAXED, __HIP_MEMORY_SCOPE_AGENT);
}
__device__ __forceinline__ short8 ld16_llc(const u16* p) {
  const u64* q = (const u64*)p;
  u64 lo = ld8_llc(q), hi = ld8_llc(q + 1);
  union { u64 v[2]; short8 s; } u;
  u.v[0] = lo; u.v[1] = hi;
  return u.s;
}
__device__ __forceinline__ void st2_llc(u16* p, u16 v) {
  __hip_atomic_store(p, v, __ATOMIC_RELAXED, __HIP_MEMORY_SCOPE_AGENT);
}

__device__ __forceinline__ short8 cvt8(const float* src) {
  float4 lo = *(const float4*)src;
  float4 hi = *(const float4*)(src + 4);
  short8 fr;
  fr[0] = (short)f2bf(lo.x); fr[1] = (short)f2bf(lo.y);
  fr[2] = (short)f2bf(lo.z); fr[3] = (short)f2bf(lo.w);
  fr[4] = (short)f2bf(hi.x); fr[5] = (short)f2bf(hi.y);
  fr[6] = (short)f2bf(hi.z); fr[7] = (short)f2bf(hi.w);
  return fr;
}

// ---- embedding gather into MFMA-B fragment layout (bf16), R7 layout ----
__global__ void gather_x0(const int* __restrict__ in_t, const float* __restrict__ emb,
                          u16* __restrict__ x0) {
  int gid = blockIdx.x * 256 + threadIdx.x;
  int c = gid >> 6, lane = gid & 63;
  int t = c >> 6, rem = c & 63;
  int kt = rem >> 2, nt = rem & 3;
  int b = nt * 16 + (lane & 15);
  int k0 = kt * 32 + ((lane >> 4) * 8);
  int row = in_t[b * T_LEN + t];
  *(short8*)(x0 + (size_t)c * CHUNK_U16 + lane * 8) =
      cvt8(emb + (size_t)row * 512 + k0);
}

// ---- persistent recurrent kernel, tag-embedded h exchange ----
// 128 blocks x 256 threads. bid: g=bid&3 (layer=g>>1, sb=g&1), i=bid>>2 (0..31).
// Unit: h [16i,16i+16) x samples [32sb,32sb+32). Waves: w<2 x-side (Wx K=512,
// wave covers kt 8(w&1)..+8); w>=2 h-side (Wh, tagged eff-K 1024, wave covers
// tagged-kt 16(w&1)..+16). h-exchange qword (16B) = 2 halves, each u64 =
// {c(h0),c(h0+1),tag u32}; qword Q covers h 4Q..4Q+3.
__global__ __launch_bounds__(256, 1) void lstm_persist(
    const float* __restrict__ wx, const float* __restrict__ bx,
    const float* __restrict__ wh, const float* __restrict__ bh,
    const u16* __restrict__ x0, u16* __restrict__ y0,
    u16* __restrict__ hd, float* __restrict__ pool, u32* __restrict__ yflg) {
  __shared__ float part[4][64][34];

  const int tid = threadIdx.x;
  const int w = tid >> 6, lane = tid & 63;
  const int q = lane >> 4, col = lane & 15;
  const int bid = blockIdx.x;
  const int g = bid & 3;
  const int layer = g >> 1, sb = g & 1;
  const int i = bid >> 2;          // 0..31
  const int side = w >> 1;

  // ---- weight fragments ----
  // x-side: afrag[mt][ks] over K=512 half (w&1); h-side: tag-layout slots.
  short8 afx[4][8];    // x-side only
  short8 afh[4][16];   // h-side only
  {
    const int gt = col & 3, hl4 = col >> 2;
#pragma unroll
    for (int mt = 0; mt < 4; ++mt) {
      const int h_out = i * 16 + mt * 4 + hl4;
      if (side == 0) {
        const float* wrow = wx + ((size_t)(layer * 4 + gt) * 512 + h_out) * 512;
        const int kb = (w & 1) * 256 + q * 8;
#pragma unroll
        for (int ks = 0; ks < 8; ++ks)
          afx[mt][ks] = cvt8(wrow + kb + ks * 32);
      } else {
        const float* wrow = wh + ((size_t)(layer * 4 + gt) * 512 + h_out) * 512;
#pragma unroll
        for (int ktl = 0; ktl < 16; ++ktl) {
          const int ktg = (w & 1) * 16 + ktl;
          const int hb = 4 * (4 * ktg + q);   // input-h base of this octet/qword
          short8 fr;
          fr[0] = (short)f2bf(wrow[hb + 0]);
          fr[1] = (short)f2bf(wrow[hb + 1]);
          fr[2] = 0; fr[3] = 0;               // tag slots: zero weight
          fr[4] = (short)f2bf(wrow[hb + 2]);
          fr[5] = (short)f2bf(wrow[hb + 3]);
          fr[6] = 0; fr[7] = 0;
          afh[mt][ktl] = fr;
        }
      }
    }
  }

  // epilogue ownership: h-pair (16i+2p, +1) x sample n
  const int p = tid >> 5, n = tid & 31;   // p 0..7
  float biasv[2][4];
  size_t offY[2];
#pragma unroll
  for (int P = 0; P < 2; ++P) {
    const int h_g = i * 16 + 2 * p + P;
#pragma unroll
    for (int r = 0; r < 4; ++r)
      biasv[P][r] = bx[(layer * 4 + r) * 512 + h_g] + bh[(layer * 4 + r) * 512 + h_g];
    offY[P] = ((size_t)((h_g >> 5) * 4 + sb * 2 + (n >> 4)) * 64 +
               (n & 15) + 16 * ((h_g >> 3) & 3)) * 8 + (h_g & 7);
  }
  // h-store u64 index: qword = 4i + (p>>1), half = p&1
  const size_t hoff = ((size_t)(4 * i + (p >> 1)) * 32 + n) * 2 + (p & 1);

  const u16* xl = layer ? y0 : x0;
  u16* hdl = hd + (size_t)g * 2 * GSLOT_U16;
  u32* yf_own = yflg + sb * 32 + i;
  const u32* yf_grp = yflg + sb * 32;

  float2 cst = {0.f, 0.f};
  float2 opool = {0.f, 0.f};

  for (int t = 0; t < T_LEN; ++t) {
    // ================= compute phase =================
    if (side == 0) {
      if (layer == 1) {
        const u32 ty = (u32)(t + 1);
        const u32* pf = yf_grp + (lane & 31);
        for (;;) {
          u32 v = __hip_atomic_load(pf, __ATOMIC_RELAXED, __HIP_MEMORY_SCOPE_AGENT);
          if (__all((int)(v >= ty))) break;
          __builtin_amdgcn_s_sleep(1);
        }
        asm volatile("" ::: "memory");
      }
      const u16* xs = xl + (size_t)t * XSTEP_U16;
      f32x4 acc[4][2] = {};
#pragma unroll
      for (int ks = 0; ks < 8; ++ks) {
        const int ktl = (w & 1) * 8 + ks;
        const u16* pp = xs + ((size_t)(ktl * 4 + 2 * sb) * 64 + lane) * 8;
        short8 f0, f1;
        if (layer == 0) {
          f0 = *(const short8*)pp;
          f1 = *(const short8*)(pp + CHUNK_U16);
        } else {
          f0 = ld16_llc(pp);
          f1 = ld16_llc(pp + CHUNK_U16);
        }
#pragma unroll
        for (int mt = 0; mt < 4; ++mt) {
          acc[mt][0] = __builtin_amdgcn_mfma_f32_16x16x32_bf16(afx[mt][ks], f0,
                                                               acc[mt][0], 0, 0, 0);
          acc[mt][1] = __builtin_amdgcn_mfma_f32_16x16x32_bf16(afx[mt][ks], f1,
                                                               acc[mt][1], 0, 0, 0);
        }
      }
#pragma unroll
      for (int mt = 0; mt < 4; ++mt)
#pragma unroll
        for (int ntl = 0; ntl < 2; ++ntl)
#pragma unroll
          for (int r = 0; r < 4; ++r)
            part[w][mt * 16 + q * 4 + r][ntl * 16 + col] = acc[mt][ntl][r];
    } else {
      // ---- h-side: tagged retry loads (detect+data in one round) ----
      const u64* hb = (const u64*)(hdl + (size_t)(t & 1) * GSLOT_U16);
      const u32 tagv = (u32)t;
      u64 flo[16][2], fhi[16][2];
      for (;;) {
#pragma unroll
        for (int ktl = 0; ktl < 16; ++ktl) {
          const int ktg = (w & 1) * 16 + ktl;
#pragma unroll
          for (int ntl = 0; ntl < 2; ++ntl) {
            const u64* pp = hb + ((size_t)((4 * ktg + q) * 32 + 16 * ntl + col)) * 2;
            flo[ktl][ntl] = ld8_llc(pp);
            fhi[ktl][ntl] = ld8_llc(pp + 1);
          }
        }
        int ok = 1;
#pragma unroll
        for (int ktl = 0; ktl < 16; ++ktl)
#pragma unroll
          for (int ntl = 0; ntl < 2; ++ntl)
            ok &= (int)(((u32)(flo[ktl][ntl] >> 32) == tagv) &
                        ((u32)(fhi[ktl][ntl] >> 32) == tagv));
        if (__all(ok)) break;
      }
      f32x4 acc[4][2] = {};
#pragma unroll
      for (int ktl = 0; ktl < 16; ++ktl) {
#pragma unroll
        for (int ntl = 0; ntl < 2; ++ntl) {
          union { u64 v[2]; short8 s; } u;
          u.v[0] = flo[ktl][ntl]; u.v[1] = fhi[ktl][ntl];
#pragma unroll
          for (int mt = 0; mt < 4; ++mt)
            acc[mt][ntl] = __builtin_amdgcn_mfma_f32_16x16x32_bf16(
                afh[mt][ktl], u.s, acc[mt][ntl], 0, 0, 0);
        }
      }
#pragma unroll
      for (int mt = 0; mt < 4; ++mt)
#pragma unroll
        for (int ntl = 0; ntl < 2; ++ntl)
#pragma unroll
          for (int r = 0; r < 4; ++r)
            part[w][mt * 16 + q * 4 + r][ntl * 16 + col] = acc[mt][ntl][r];
    }
    __syncthreads();   // b1: partials ready

    // ================= epilogue: reduce + gates + tagged h store =================
    u64* hdst = (u64*)(hdl + (size_t)((t + 1) & 1) * GSLOT_U16);
    u16* ydst = y0 + (size_t)t * XSTEP_U16;
    float cn2[2], og2[2];
#pragma unroll
    for (int P = 0; P < 2; ++P) {
      const int rbase = 8 * p + 4 * P;
      float vg[4];
#pragma unroll
      for (int gt = 0; gt < 4; ++gt)
        vg[gt] = part[0][rbase + gt][n] + part[1][rbase + gt][n] +
                 part[2][rbase + gt][n] + part[3][rbase + gt][n] + biasv[P][gt];
      const float ig = sigf(vg[0]);
      const float fg = sigf(vg[1]);
      const float gg = tanhfast(vg[2]);
      const float og = sigf(vg[3]);
      const float cp = P ? cst.y : cst.x;
      const float cn = fg * cp + ig * gg;   // c input = prev h_new (unpack bug)
      const float hn = og * tanhfast(cn);
      if (P) cst.y = hn; else cst.x = hn;
      cn2[P] = cn; og2[P] = og;
    }
    // single tagged u64: {c0, c1, tag = t+1} -> c_new is next h-input (bug)
    {
      u64 val = (u64)(u16)f2bf(cn2[0]) | ((u64)(u16)f2bf(cn2[1]) << 16) |
                ((u64)(u32)(t + 1) << 32);
      st8_llc(hdst + hoff, val);
    }
    if (layer == 0) {
      st2_llc(ydst + offY[0], f2bf(og2[0]));   // o-gate -> L1 input
      st2_llc(ydst + offY[1], f2bf(og2[1]));
      asm volatile("s_waitcnt vmcnt(0)" ::: "memory");
      __syncthreads();   // b2: y stores acked; part[] fully read
      if (tid == 0)
        __hip_atomic_store(yf_own, (u32)(t + 1), __ATOMIC_RELAXED,
                           __HIP_MEMORY_SCOPE_AGENT);
    } else {
      opool.x += og2[0]; opool.y += og2[1];
      __syncthreads();   // b2: part[] fully read
    }
  }

  if (layer == 1) {
    pool[(size_t)(i * 16 + 2 * p) * 64 + sb * 32 + n] = opool.x;
    pool[(size_t)(i * 16 + 2 * p + 1) * 64 + sb * 32 + n] = opool.y;
  }
}

// ---- final pooled @ wo.T + bo -> sigmoid ----
__global__ void finalize_k(const float* __restrict__ pool, const float* __restrict__ wo,
                           const float* __restrict__ bo, float* __restrict__ out) {
  const int b = threadIdx.x;
  float s = 0.f;
  for (int h = 0; h < 512; ++h) s += pool[h * 64 + b] * wo[h];
  out[b] = sigf(s * (1.f / 256.f) + bo[0]);
}

extern "C" void kernel_launch(void* const* d_in, const int* in_sizes, int n_in,
                              void* d_out, int out_size, void* d_ws, size_t ws_size,
                              hipStream_t stream) {
  const int* in_t = (const int*)d_in[0];
  const float* emb = (const float*)d_in[1];
  const float* wx = (const float*)d_in[2];
  const float* bx = (const float*)d_in[3];
  const float* wh = (const float*)d_in[4];
  const float* bh = (const float*)d_in[5];
  const float* wo = (const float*)d_in[6];
  const float* bo = (const float*)d_in[7];
  float* out = (float*)d_out;
  char* ws = (char*)d_ws;
  u16* x0 = (u16*)(ws + OFF_X0);
  u16* y0 = (u16*)(ws + OFF_Y0);
  u16* hd = (u16*)(ws + OFF_HD);
  float* pool = (float*)(ws + OFF_POOL);
  u32* yflg = (u32*)(ws + OFF_YFLG);

  hipMemsetAsync(ws + OFF_HD, 0, SZ_HD, stream);     // h(0)=0, tags=0
  hipMemsetAsync(ws + OFF_YFLG, 0, SZ_YFLG, stream); // y step flags
  gather_x0<<<4096, 256, 0, stream>>>(in_t, emb, x0);
  lstm_persist<<<128, 256, 0, stream>>>(wx, bx, wh, bh, x0, y0, hd, pool, yflg);
  finalize_k<<<1, 64, 0, stream>>>(pool, wo, bo, out);
}

// Round 11
// 1148.661 us; speedup vs baseline: 1.4854x; 1.4854x over previous
//
#include <hip/hip_runtime.h>

typedef __attribute__((ext_vector_type(8))) short short8;
typedef __attribute__((ext_vector_type(4))) float f32x4;
typedef unsigned short u16;
typedef unsigned int u32;
typedef unsigned long long u64;

#define T_LEN 256
#define XSTEP_U16 32768      // x/y per-t: [sbb:4][kt:16][512] u16 = 64KB
#define GSLOT_U16 8192       // h-exchange per group per slot: [kt:16][512] u16 = 16KB

// workspace layout (bytes)
#define OFF_X0 0u
#define SZ_X0 (256u * 65536u)   // 16MB
#define OFF_Y0 (OFF_X0 + SZ_X0)
#define SZ_Y0 SZ_X0             // 16MB
#define OFF_HD (OFF_Y0 + SZ_Y0)
#define SZ_HD (8u * 2u * 16384u)  // 8 groups x 2 slots x 16KB
#define OFF_POOL (OFF_HD + SZ_HD)
#define SZ_POOL (512u * 64u * 4u)
#define OFF_HFLG (OFF_POOL + SZ_POOL)
#define SZ_HFLG (8u * 128u)     // [group]: 16 packed u32 flags, 128B stride
#define OFF_YFLG (OFF_HFLG + SZ_HFLG)
#define SZ_YFLG (4u * 128u)     // [sbb]: 16 packed u32 flags
#define OFF_XMAP (OFF_YFLG + SZ_YFLG)
#define SZ_XMAP (8u * 16u * 4u) // [group][16] published XCC ids

__device__ __forceinline__ u16 f2bf(float x) {
  unsigned u = __builtin_bit_cast(unsigned, x);
  return (u16)((u + 0x7fffu + ((u >> 16) & 1u)) >> 16);
}
__device__ __forceinline__ float sigf(float x) { return 1.f / (1.f + __expf(-x)); }
__device__ __forceinline__ float tanhfast(float x) {
  float e = __expf(2.f * x);
  return 1.f - 2.f / (e + 1.f);
}

// sc1 (LLC-coherent) relaxed primitives — proven global path
__device__ __forceinline__ short8 ld16_llc(const u16* p) {
  const u64* q = (const u64*)p;
  u64 lo = __hip_atomic_load(q + 0, __ATOMIC_RELAXED, __HIP_MEMORY_SCOPE_AGENT);
  u64 hi = __hip_atomic_load(q + 1, __ATOMIC_RELAXED, __HIP_MEMORY_SCOPE_AGENT);
  union { u64 v[2]; short8 s; } u;
  u.v[0] = lo; u.v[1] = hi;
  return u.s;
}
__device__ __forceinline__ void st2_llc(u16* p, u16 v) {
  __hip_atomic_store(p, v, __ATOMIC_RELAXED, __HIP_MEMORY_SCOPE_AGENT);
}
__device__ __forceinline__ void st4_llc(u32* p, u32 v) {
  __hip_atomic_store(p, v, __ATOMIC_RELAXED, __HIP_MEMORY_SCOPE_AGENT);
}
__device__ __forceinline__ u32 ld4_llc(const u32* p) {
  return __hip_atomic_load(p, __ATOMIC_RELAXED, __HIP_MEMORY_SCOPE_AGENT);
}
// poll 16 packed flags via sc1 (one line)
__device__ __forceinline__ void poll_sc1(const u32* base, int lane, u32 tgt, bool slp) {
  const u32* pf = base + (lane & 15);
  for (;;) {
    u32 v = ld4_llc(pf);
    if (__all((int)(v >= tgt))) break;
    if (slp) __builtin_amdgcn_s_sleep(1);
  }
  asm volatile("" ::: "memory");
}
// intra-XCD fast poll: invalidate own L1, plain load hits shared L2
__device__ __forceinline__ void poll_fast(const u32* base, int lane, u32 tgt) {
  const volatile u32* pf = base + (lane & 15);
  for (;;) {
    asm volatile("buffer_inv" ::: "memory");
    u32 v = *pf;
    if (__all((int)(v >= tgt))) break;
  }
  asm volatile("" ::: "memory");
}

__device__ __forceinline__ short8 cvt8(const float* src) {
  float4 lo = *(const float4*)src;
  float4 hi = *(const float4*)(src + 4);
  short8 fr;
  fr[0] = (short)f2bf(lo.x); fr[1] = (short)f2bf(lo.y);
  fr[2] = (short)f2bf(lo.z); fr[3] = (short)f2bf(lo.w);
  fr[4] = (short)f2bf(hi.x); fr[5] = (short)f2bf(hi.y);
  fr[6] = (short)f2bf(hi.z); fr[7] = (short)f2bf(hi.w);
  return fr;
}

// ---- embedding gather: [t][sbb:4][kt:16][512] fragment layout ----
__global__ void gather_x0(const int* __restrict__ in_t, const float* __restrict__ emb,
                          u16* __restrict__ x0) {
  int gid = blockIdx.x * 256 + threadIdx.x;
  int c = gid >> 6, lane = gid & 63;
  int t = c >> 6, rem = c & 63;
  int sbb = rem >> 4, kt = rem & 15;
  int b = sbb * 16 + (lane & 15);
  int k0 = kt * 32 + ((lane >> 4) * 8);
  int row = in_t[b * T_LEN + t];
  *(short8*)(x0 + (size_t)c * 512 + lane * 8) = cvt8(emb + (size_t)row * 512 + k0);
}

// ---- main loop, specialized on exchange path ----
// group g=(layer,sbb): 16 blocks, 16 samples, all 512 h. Block i owns h [32i,32i+32).
// 8 waves: side=w>>2 (0 x / 1 h), kq=(w>>1)&1 (K-half), mh=w&1 (16h half).
// afrag[4][8] = 128 VGPRs (spill-free).
template <bool FAST>
__device__ __forceinline__ void run_loop(
    int layer, int sbb, int g2, int i, int w, int lane, int tid,
    const float* __restrict__ wx, const float* __restrict__ bx,
    const float* __restrict__ wh, const float* __restrict__ bh,
    const u16* __restrict__ x0, u16* __restrict__ y0,
    u16* __restrict__ hd, float* __restrict__ pool,
    u32* __restrict__ hflg, u32* __restrict__ yflg,
    float (*part)[64][17]) {
  const int side = w >> 2, kq = (w >> 1) & 1, mh = w & 1;
  const int q = lane >> 4, col = lane & 15;

  // ---- weight fragments: 4 m-tiles x 8 ks over this (side, kq) ----
  short8 afrag[4][8];
  {
    const int gt_a = col & 3, hsub = col >> 2;
#pragma unroll
    for (int mt = 0; mt < 4; ++mt) {
      const int h_g = i * 32 + mh * 16 + mt * 4 + hsub;
      const float* wrow = (side ? wh : wx) +
                          ((size_t)(layer * 4 + gt_a) * 512 + h_g) * 512;
#pragma unroll
      for (int ks = 0; ks < 8; ++ks)
        afrag[mt][ks] = cvt8(wrow + kq * 256 + ks * 32 + q * 8);
    }
  }
  // epilogue ownership: one (h = 32i+hl, sample n)
  const int hl = tid >> 4, n = tid & 15;
  float bias[4];
#pragma unroll
  for (int r = 0; r < 4; ++r) {
    const int h_g = i * 32 + hl;
    bias[r] = bx[(layer * 4 + r) * 512 + h_g] + bh[(layer * 4 + r) * 512 + h_g];
  }
  const size_t coff = (size_t)i * 512 + ((size_t)((hl >> 3) * 16 + n)) * 8 + (hl & 7);
  const int mhs = hl >> 4;
  const int lr = ((hl & 15) >> 2) * 16 + ((hl & 15) & 3) * 4;

  const u16* xbase = layer ? y0 : x0;
  u16* hdl = hd + (size_t)g2 * 2 * GSLOT_U16;
  u32* hf_own = hflg + g2 * 32 + i;
  const u32* hf_grp = hflg + g2 * 32;
  u32* yf_own = yflg + sbb * 32 + i;
  const u32* yf_grp = yflg + sbb * 32;

  float cst = 0.f, opool = 0.f;

  for (int t = 0; t < T_LEN; ++t) {
    f32x4 acc[4] = {};
    if (side == 0) {
      if (layer == 1) poll_sc1(yf_grp, lane, (u32)(t + 1), true);
      const u16* src = xbase + (size_t)t * XSTEP_U16 + (size_t)sbb * GSLOT_U16;
#pragma unroll
      for (int ks = 0; ks < 8; ++ks) {
        const u16* p = src + (kq * 8 + ks) * 512 + lane * 8;
        short8 f = (layer == 0) ? *(const short8*)p : ld16_llc(p);
#pragma unroll
        for (int mt = 0; mt < 4; ++mt)
          acc[mt] = __builtin_amdgcn_mfma_f32_16x16x32_bf16(afrag[mt][ks], f,
                                                            acc[mt], 0, 0, 0);
      }
    } else {
      if (FAST) poll_fast(hf_grp, lane, (u32)t);
      else poll_sc1(hf_grp, lane, (u32)t, false);
      const u16* src = hdl + (size_t)(t & 1) * GSLOT_U16;
#pragma unroll
      for (int ks = 0; ks < 8; ++ks) {
        const u16* p = src + (kq * 8 + ks) * 512 + lane * 8;
        short8 f = FAST ? *(const short8*)p : ld16_llc(p);
#pragma unroll
        for (int mt = 0; mt < 4; ++mt)
          acc[mt] = __builtin_amdgcn_mfma_f32_16x16x32_bf16(afrag[mt][ks], f,
                                                            acc[mt], 0, 0, 0);
      }
    }
    // partials -> LDS (C/D: col n = lane&15, tile row = 4q + r)
#pragma unroll
    for (int mt = 0; mt < 4; ++mt)
#pragma unroll
      for (int r = 0; r < 4; ++r)
        part[w][mt * 16 + q * 4 + r][col] = acc[mt][r];
    __syncthreads();   // b1: partials ready

    // ---- epilogue: sum 4 contributing waves + gates + c-store ----
    float v[4];
#pragma unroll
    for (int gt = 0; gt < 4; ++gt)
      v[gt] = part[mhs][lr + gt][n] + part[2 + mhs][lr + gt][n] +
              part[4 + mhs][lr + gt][n] + part[6 + mhs][lr + gt][n] + bias[gt];
    const float ig = sigf(v[0]);
    const float fg = sigf(v[1]);
    const float gg = tanhfast(v[2]);
    const float og = sigf(v[3]);
    const float cn = fg * cst + ig * gg;   // c input = prev h_new (unpack bug)
    const float hn = og * tanhfast(cn);
    cst = hn;
    {
      u16* hdst = hdl + (size_t)((t + 1) & 1) * GSLOT_U16;
      if (FAST) *(volatile u16*)(hdst + coff) = f2bf(cn);  // plain -> L2 (bug: c_new is h-input)
      else st2_llc(hdst + coff, f2bf(cn));
    }
    asm volatile("s_waitcnt vmcnt(0)" ::: "memory");  // c acked (L2 if FAST); y(t-1) acked too
    __syncthreads();   // b2: all stores acked; part[] fully read
    if (tid == 0) {
      if (FAST) *(volatile u32*)hf_own = (u32)(t + 1);
      else st4_llc(hf_own, (u32)(t + 1));
    }
    if (layer == 0) {
      if (tid == 1) st4_llc(yf_own, (u32)t);   // certify y(t-1) (acked by this vmcnt)
      // y(t) fire-and-forget via sc1; certified next step
      st2_llc(y0 + (size_t)t * XSTEP_U16 + (size_t)sbb * GSLOT_U16 + coff, f2bf(og));
    } else {
      opool += og;
    }
  }

  if (layer == 0) {
    asm volatile("s_waitcnt vmcnt(0)" ::: "memory");
    __syncthreads();
    if (tid == 1) st4_llc(yf_own, (u32)T_LEN);   // certify y(255)
  } else {
    pool[(size_t)(i * 32 + hl) * 64 + sbb * 16 + n] = opool;
  }
}

// ---- persistent kernel: publish XCC id, per-group path decision, run ----
__global__ __launch_bounds__(512, 2) void lstm_persist(
    const float* __restrict__ wx, const float* __restrict__ bx,
    const float* __restrict__ wh, const float* __restrict__ bh,
    const u16* __restrict__ x0, u16* __restrict__ y0,
    u16* __restrict__ hd, float* __restrict__ pool,
    u32* __restrict__ hflg, u32* __restrict__ yflg, u32* __restrict__ xmap) {
  __shared__ float part[8][64][17];
  const int tid = threadIdx.x;
  const int w = tid >> 6, lane = tid & 63;
  const int bid = blockIdx.x;
  const int g2 = bid & 7;                // expected XCD slot = group
  const int layer = g2 >> 2, sbb = g2 & 3;
  const int i = bid >> 3;                // 0..15

  u32* map_g = xmap + g2 * 16;
  if (tid == 0) {
    u32 my;
    asm volatile("s_getreg_b32 %0, hwreg(HW_REG_XCC_ID)" : "=s"(my));
    st4_llc(map_g + i, my & 0xFu);
  }
  const u32* map_f = xmap + (((g2 + 1) & 7) * 16);
  bool fast;
  {
    u32 v, f0;
    for (;;) {
      v = ld4_llc(map_g + (lane & 15));
      f0 = ld4_llc(map_f + (lane & 15));
      if (__all((int)((v != 0xFFFFFFFFu) & (f0 != 0xFFFFFFFFu)))) break;
      __builtin_amdgcn_s_sleep(2);
    }
    u32 ref = (u32)__shfl((int)v, 0);
    fast = __all((int)(v == ref)) && __all((int)(f0 != ref));
  }
  __syncthreads();

  if (fast)
    run_loop<true>(layer, sbb, g2, i, w, lane, tid, wx, bx, wh, bh, x0, y0, hd,
                   pool, hflg, yflg, part);
  else
    run_loop<false>(layer, sbb, g2, i, w, lane, tid, wx, bx, wh, bh, x0, y0, hd,
                    pool, hflg, yflg, part);
}

// ---- final pooled @ wo.T + bo -> sigmoid ----
__global__ void finalize_k(const float* __restrict__ pool, const float* __restrict__ wo,
                           const float* __restrict__ bo, float* __restrict__ out) {
  const int b = threadIdx.x;
  float s = 0.f;
  for (int h = 0; h < 512; ++h) s += pool[h * 64 + b] * wo[h];
  out[b] = sigf(s * (1.f / 256.f) + bo[0]);
}

extern "C" void kernel_launch(void* const* d_in, const int* in_sizes, int n_in,
                              void* d_out, int out_size, void* d_ws, size_t ws_size,
                              hipStream_t stream) {
  const int* in_t = (const int*)d_in[0];
  const float* emb = (const float*)d_in[1];
  const float* wx = (const float*)d_in[2];
  const float* bx = (const float*)d_in[3];
  const float* wh = (const float*)d_in[4];
  const float* bh = (const float*)d_in[5];
  const float* wo = (const float*)d_in[6];
  const float* bo = (const float*)d_in[7];
  float* out = (float*)d_out;
  char* ws = (char*)d_ws;
  u16* x0 = (u16*)(ws + OFF_X0);
  u16* y0 = (u16*)(ws + OFF_Y0);
  u16* hd = (u16*)(ws + OFF_HD);
  float* pool = (float*)(ws + OFF_POOL);
  u32* hflg = (u32*)(ws + OFF_HFLG);
  u32* yflg = (u32*)(ws + OFF_YFLG);
  u32* xmap = (u32*)(ws + OFF_XMAP);

  hipMemsetAsync(ws + OFF_HD, 0, SZ_HD, stream);                 // h(0) = 0
  hipMemsetAsync(ws + OFF_HFLG, 0, SZ_HFLG + SZ_YFLG, stream);   // step flags
  hipMemsetAsync(ws + OFF_XMAP, 0xFF, SZ_XMAP, stream);          // id markers
  gather_x0<<<4096, 256, 0, stream>>>(in_t, emb, x0);
  lstm_persist<<<128, 512, 0, stream>>>(wx, bx, wh, bh, x0, y0, hd, pool,
                                        hflg, yflg, xmap);
  finalize_k<<<1, 64, 0, stream>>>(pool, wo, bo, out);
}

// Round 12
// 1130.204 us; speedup vs baseline: 1.5097x; 1.0163x over previous
//
#include <hip/hip_runtime.h>

typedef __attribute__((ext_vector_type(8))) short short8;
typedef __attribute__((ext_vector_type(4))) float f32x4;
typedef unsigned short u16;
typedef unsigned int u32;
typedef unsigned long long u64;

#define T_LEN 256
#define XSTEP_U16 32768      // x/y per-t: [sbb:4][kt:16][512] u16 = 64KB
#define GSLOT_U16 8192       // h-exchange per (layer,sbb) per slot: 16KB

// workspace layout (bytes)
#define OFF_X0 0u
#define SZ_X0 (256u * 65536u)   // 16MB
#define OFF_Y0 (OFF_X0 + SZ_X0)
#define SZ_Y0 SZ_X0             // 16MB
#define OFF_HD (OFF_Y0 + SZ_Y0)
#define SZ_HD (8u * 2u * 16384u)  // 8 h-domains x 2 slots x 16KB
#define OFF_POOL (OFF_HD + SZ_HD)
#define SZ_POOL (512u * 64u * 4u)
#define OFF_HFLG (OFF_POOL + SZ_POOL)
#define SZ_HFLG (8u * 128u)     // [layer*4+sbb]: 16 packed u32 flags
#define OFF_YFLG (OFF_HFLG + SZ_HFLG)
#define SZ_YFLG (4u * 128u)     // [sbb]: 16 packed u32 flags
#define OFF_XMAP (OFF_YFLG + SZ_YFLG)
#define SZ_XMAP (4u * 32u * 4u) // [sbb][32] published XCC ids

__device__ __forceinline__ u16 f2bf(float x) {
  unsigned u = __builtin_bit_cast(unsigned, x);
  return (u16)((u + 0x7fffu + ((u >> 16) & 1u)) >> 16);
}
__device__ __forceinline__ float sigf(float x) { return 1.f / (1.f + __expf(-x)); }
__device__ __forceinline__ float tanhfast(float x) {
  float e = __expf(2.f * x);
  return 1.f - 2.f / (e + 1.f);
}

// sc1 (LLC-coherent) relaxed primitives — fallback path
__device__ __forceinline__ short8 ld16_llc(const u16* p) {
  const u64* q = (const u64*)p;
  u64 lo = __hip_atomic_load(q + 0, __ATOMIC_RELAXED, __HIP_MEMORY_SCOPE_AGENT);
  u64 hi = __hip_atomic_load(q + 1, __ATOMIC_RELAXED, __HIP_MEMORY_SCOPE_AGENT);
  union { u64 v[2]; short8 s; } u;
  u.v[0] = lo; u.v[1] = hi;
  return u.s;
}
__device__ __forceinline__ void st2_llc(u16* p, u16 v) {
  __hip_atomic_store(p, v, __ATOMIC_RELAXED, __HIP_MEMORY_SCOPE_AGENT);
}
__device__ __forceinline__ void st4_llc(u32* p, u32 v) {
  __hip_atomic_store(p, v, __ATOMIC_RELAXED, __HIP_MEMORY_SCOPE_AGENT);
}
__device__ __forceinline__ u32 ld4_llc(const u32* p) {
  return __hip_atomic_load(p, __ATOMIC_RELAXED, __HIP_MEMORY_SCOPE_AGENT);
}
__device__ __forceinline__ void poll_sc1(const u32* base, int lane, u32 tgt, bool slp) {
  const u32* pf = base + (lane & 15);
  for (;;) {
    u32 v = ld4_llc(pf);
    if (__all((int)(v >= tgt))) break;
    if (slp) __builtin_amdgcn_s_sleep(1);
  }
  asm volatile("" ::: "memory");
}
// intra-XCD fast poll: invalidate own L1, plain load hits shared L2
__device__ __forceinline__ void poll_fast(const u32* base, int lane, u32 tgt) {
  const volatile u32* pf = base + (lane & 15);
  for (;;) {
    asm volatile("buffer_inv" ::: "memory");
    u32 v = *pf;
    if (__all((int)(v >= tgt))) break;
  }
  asm volatile("" ::: "memory");
}

__device__ __forceinline__ short8 cvt8(const float* src) {
  float4 lo = *(const float4*)src;
  float4 hi = *(const float4*)(src + 4);
  short8 fr;
  fr[0] = (short)f2bf(lo.x); fr[1] = (short)f2bf(lo.y);
  fr[2] = (short)f2bf(lo.z); fr[3] = (short)f2bf(lo.w);
  fr[4] = (short)f2bf(hi.x); fr[5] = (short)f2bf(hi.y);
  fr[6] = (short)f2bf(hi.z); fr[7] = (short)f2bf(hi.w);
  return fr;
}

// ---- embedding gather: [t][sbb:4][kt:16][512] fragment layout ----
__global__ void gather_x0(const int* __restrict__ in_t, const float* __restrict__ emb,
                          u16* __restrict__ x0) {
  int gid = blockIdx.x * 256 + threadIdx.x;
  int c = gid >> 6, lane = gid & 63;
  int t = c >> 6, rem = c & 63;
  int sbb = rem >> 4, kt = rem & 15;
  int b = sbb * 16 + (lane & 15);
  int k0 = kt * 32 + ((lane >> 4) * 8);
  int row = in_t[b * T_LEN + t];
  *(short8*)(x0 + (size_t)c * 512 + lane * 8) = cvt8(emb + (size_t)row * 512 + k0);
}

// ---- main loop, specialized on exchange path ----
// group sbb: 32 blocks (16 units x 2 layers), 16 samples, all 512 h, ONE XCD.
// Unit i owns h [32i,32i+32). 8 waves: side=w>>2 (0 x / 1 h), kq=(w>>1)&1, mh=w&1.
template <bool FAST>
__device__ __forceinline__ void run_loop(
    int layer, int sbb, int i, int w, int lane, int tid,
    const float* __restrict__ wx, const float* __restrict__ bx,
    const float* __restrict__ wh, const float* __restrict__ bh,
    const u16* __restrict__ x0, u16* __restrict__ y0,
    u16* __restrict__ hd, float* __restrict__ pool,
    u32* __restrict__ hflg, u32* __restrict__ yflg,
    float (*part)[64][17]) {
  const int side = w >> 2, kq = (w >> 1) & 1, mh = w & 1;
  const int q = lane >> 4, col = lane & 15;
  const int hdom = layer * 4 + sbb;

  // ---- weight fragments: 4 m-tiles x 8 ks over this (side, kq) ----
  short8 afrag[4][8];
  {
    const int gt_a = col & 3, hsub = col >> 2;
#pragma unroll
    for (int mt = 0; mt < 4; ++mt) {
      const int h_g = i * 32 + mh * 16 + mt * 4 + hsub;
      const float* wrow = (side ? wh : wx) +
                          ((size_t)(layer * 4 + gt_a) * 512 + h_g) * 512;
#pragma unroll
      for (int ks = 0; ks < 8; ++ks)
        afrag[mt][ks] = cvt8(wrow + kq * 256 + ks * 32 + q * 8);
    }
  }
  // epilogue ownership: one (h = 32i+hl, sample n)
  const int hl = tid >> 4, n = tid & 15;
  float bias[4];
#pragma unroll
  for (int r = 0; r < 4; ++r) {
    const int h_g = i * 32 + hl;
    bias[r] = bx[(layer * 4 + r) * 512 + h_g] + bh[(layer * 4 + r) * 512 + h_g];
  }
  const size_t coff = (size_t)i * 512 + ((size_t)((hl >> 3) * 16 + n)) * 8 + (hl & 7);
  const int mhs = hl >> 4;
  const int lr = ((hl & 15) >> 2) * 16 + ((hl & 15) & 3) * 4;

  const u16* xbase = layer ? y0 : x0;
  u16* hdl = hd + (size_t)hdom * 2 * GSLOT_U16;
  u32* hf_own = hflg + hdom * 32 + i;
  const u32* hf_grp = hflg + hdom * 32;
  u32* yf_own = yflg + sbb * 32 + i;
  const u32* yf_grp = yflg + sbb * 32;

  float cst = 0.f, opool = 0.f;

  for (int t = 0; t < T_LEN; ++t) {
    f32x4 acc[4] = {};
    if (side == 0) {
      if (layer == 1) {
        if (FAST) poll_fast(yf_grp, lane, (u32)(t + 1));
        else poll_sc1(yf_grp, lane, (u32)(t + 1), true);
      }
      const u16* src = xbase + (size_t)t * XSTEP_U16 + (size_t)sbb * GSLOT_U16;
#pragma unroll
      for (int ks = 0; ks < 8; ++ks) {
        const u16* p = src + (kq * 8 + ks) * 512 + lane * 8;
        short8 f = (layer == 0 || FAST) ? *(const short8*)p : ld16_llc(p);
#pragma unroll
        for (int mt = 0; mt < 4; ++mt)
          acc[mt] = __builtin_amdgcn_mfma_f32_16x16x32_bf16(afrag[mt][ks], f,
                                                            acc[mt], 0, 0, 0);
      }
    } else {
      if (FAST) poll_fast(hf_grp, lane, (u32)t);
      else poll_sc1(hf_grp, lane, (u32)t, false);
      const u16* src = hdl + (size_t)(t & 1) * GSLOT_U16;
#pragma unroll
      for (int ks = 0; ks < 8; ++ks) {
        const u16* p = src + (kq * 8 + ks) * 512 + lane * 8;
        short8 f = FAST ? *(const short8*)p : ld16_llc(p);
#pragma unroll
        for (int mt = 0; mt < 4; ++mt)
          acc[mt] = __builtin_amdgcn_mfma_f32_16x16x32_bf16(afrag[mt][ks], f,
                                                            acc[mt], 0, 0, 0);
      }
    }
    // partials -> LDS (C/D: col n = lane&15, tile row = 4q + r)
#pragma unroll
    for (int mt = 0; mt < 4; ++mt)
#pragma unroll
      for (int r = 0; r < 4; ++r)
        part[w][mt * 16 + q * 4 + r][col] = acc[mt][r];
    __syncthreads();   // b1: partials ready

    // ---- epilogue: sum 4 contributing waves + gates + stores ----
    float v[4];
#pragma unroll
    for (int gt = 0; gt < 4; ++gt)
      v[gt] = part[mhs][lr + gt][n] + part[2 + mhs][lr + gt][n] +
              part[4 + mhs][lr + gt][n] + part[6 + mhs][lr + gt][n] + bias[gt];
    const float ig = sigf(v[0]);
    const float fg = sigf(v[1]);
    const float gg = tanhfast(v[2]);
    const float og = sigf(v[3]);
    const float cn = fg * cst + ig * gg;   // c input = prev h_new (unpack bug)
    const float hn = og * tanhfast(cn);
    cst = hn;
    {
      u16* hdst = hdl + (size_t)((t + 1) & 1) * GSLOT_U16;
      if (FAST) *(volatile u16*)(hdst + coff) = f2bf(cn);  // plain -> L2 (bug: c_new is h-input)
      else st2_llc(hdst + coff, f2bf(cn));
    }
    if (layer == 0) {
      u16* ydst = y0 + (size_t)t * XSTEP_U16 + (size_t)sbb * GSLOT_U16;
      if (FAST) *(volatile u16*)(ydst + coff) = f2bf(og);
      else st2_llc(ydst + coff, f2bf(og));
    } else {
      opool += og;
    }
    asm volatile("s_waitcnt vmcnt(0)" ::: "memory");  // stores acked (L2 if FAST)
    __syncthreads();   // b2: all stores acked; part[] fully read
    if (tid == 0) {
      if (FAST) *(volatile u32*)hf_own = (u32)(t + 1);
      else st4_llc(hf_own, (u32)(t + 1));
    }
    if (layer == 0 && tid == 1) {
      if (FAST) *(volatile u32*)yf_own = (u32)(t + 1);
      else st4_llc(yf_own, (u32)(t + 1));
    }
  }

  if (layer == 1)
    pool[(size_t)(i * 32 + hl) * 64 + sbb * 16 + n] = opool;
}

// ---- persistent kernel: publish XCC id, per-group path decision, run ----
__global__ __launch_bounds__(512, 2) void lstm_persist(
    const float* __restrict__ wx, const float* __restrict__ bx,
    const float* __restrict__ wh, const float* __restrict__ bh,
    const u16* __restrict__ x0, u16* __restrict__ y0,
    u16* __restrict__ hd, float* __restrict__ pool,
    u32* __restrict__ hflg, u32* __restrict__ yflg, u32* __restrict__ xmap) {
  __shared__ float part[8][64][17];
  const int tid = threadIdx.x;
  const int w = tid >> 6, lane = tid & 63;
  const int bid = blockIdx.x;
  const int sbb = bid & 7;             // expected XCD under round-robin
  if (sbb >= 4) return;                // surplus blocks exit
  const int j = bid >> 3;              // 0..31 within group
  const int layer = j & 1, i = j >> 1; // 16 units x 2 layers

  u32* map_g = xmap + sbb * 32;
  if (tid == 0) {
    u32 my;
    asm volatile("s_getreg_b32 %0, hwreg(HW_REG_XCC_ID)" : "=s"(my));
    st4_llc(map_g + j, my & 0xFu);
  }
  const u32* map_f = xmap + (((sbb + 1) & 3) * 32);
  bool fast;
  {
    u32 v, f0;
    for (;;) {
      v = ld4_llc(map_g + (lane & 31));
      f0 = ld4_llc(map_f + (lane & 31));
      if (__all((int)((v != 0xFFFFFFFFu) & (f0 != 0xFFFFFFFFu)))) break;
      __builtin_amdgcn_s_sleep(2);
    }
    u32 ref = (u32)__shfl((int)v, 0);
    fast = __all((int)(v == ref)) && __all((int)(f0 != ref));
  }
  __syncthreads();

  if (fast)
    run_loop<true>(layer, sbb, i, w, lane, tid, wx, bx, wh, bh, x0, y0, hd,
                   pool, hflg, yflg, part);
  else
    run_loop<false>(layer, sbb, i, w, lane, tid, wx, bx, wh, bh, x0, y0, hd,
                    pool, hflg, yflg, part);
}

// ---- final pooled @ wo.T + bo -> sigmoid ----
__global__ void finalize_k(const float* __restrict__ pool, const float* __restrict__ wo,
                           const float* __restrict__ bo, float* __restrict__ out) {
  const int b = threadIdx.x;
  float s = 0.f;
  for (int h = 0; h < 512; ++h) s += pool[h * 64 + b] * wo[h];
  out[b] = sigf(s * (1.f / 256.f) + bo[0]);
}

extern "C" void kernel_launch(void* const* d_in, const int* in_sizes, int n_in,
                              void* d_out, int out_size, void* d_ws, size_t ws_size,
                              hipStream_t stream) {
  const int* in_t = (const int*)d_in[0];
  const float* emb = (const float*)d_in[1];
  const float* wx = (const float*)d_in[2];
  const float* bx = (const float*)d_in[3];
  const float* wh = (const float*)d_in[4];
  const float* bh = (const float*)d_in[5];
  const float* wo = (const float*)d_in[6];
  const float* bo = (const float*)d_in[7];
  float* out = (float*)d_out;
  char* ws = (char*)d_ws;
  u16* x0 = (u16*)(ws + OFF_X0);
  u16* y0 = (u16*)(ws + OFF_Y0);
  u16* hd = (u16*)(ws + OFF_HD);
  float* pool = (float*)(ws + OFF_POOL);
  u32* hflg = (u32*)(ws + OFF_HFLG);
  u32* yflg = (u32*)(ws + OFF_YFLG);
  u32* xmap = (u32*)(ws + OFF_XMAP);

  hipMemsetAsync(ws + OFF_HD, 0, SZ_HD, stream);                 // h(0) = 0
  hipMemsetAsync(ws + OFF_HFLG, 0, SZ_HFLG + SZ_YFLG, stream);   // step flags
  hipMemsetAsync(ws + OFF_XMAP, 0xFF, SZ_XMAP, stream);          // id markers
  gather_x0<<<4096, 256, 0, stream>>>(in_t, emb, x0);
  lstm_persist<<<256, 512, 0, stream>>>(wx, bx, wh, bh, x0, y0, hd, pool,
                                        hflg, yflg, xmap);
  finalize_k<<<1, 64, 0, stream>>>(pool, wo, bo, out);
}

// Round 14
// 817.405 us; speedup vs baseline: 2.0874x; 1.3827x over previous
//
#include <hip/hip_runtime.h>

typedef __attribute__((ext_vector_type(8))) short short8;
typedef __attribute__((ext_vector_type(4))) float f32x4;
typedef unsigned short u16;
typedef unsigned int u32;
typedef unsigned long long u64;

#define T_LEN 256
#define XSTEP_U16 32768      // x/y per-t: [kt:16][nt:4][512] u16 = 64KB
#define CHUNK_U16 512
#define HSLOT_U64 8192       // per (layer,sb) slot: 128 Qp x 32 n x 2 u64 = 64KB

// workspace layout (bytes)
#define OFF_X0 0u
#define SZ_X0 (256u * 65536u)   // 16MB
#define OFF_Y0 (OFF_X0 + SZ_X0)
#define SZ_Y0 SZ_X0             // 16MB
#define OFF_HD (OFF_Y0 + SZ_Y0)
#define SZ_HD (4u * 2u * 65536u)  // 4 (layer,sb) domains x 2 slots x 64KB
#define OFF_POOL (OFF_HD + SZ_HD)
#define SZ_POOL (512u * 64u * 4u)
#define OFF_YFLG (OFF_POOL + SZ_POOL)
#define SZ_YFLG (2u * 32u * 4u)   // [sb][32 units] packed u32

__device__ __forceinline__ u16 f2bf(float x) {
  unsigned u = __builtin_bit_cast(unsigned, x);
  return (u16)((u + 0x7fffu + ((u >> 16) & 1u)) >> 16);
}
__device__ __forceinline__ float sigf(float x) { return 1.f / (1.f + __expf(-x)); }
__device__ __forceinline__ float tanhfast(float x) {
  float e = __expf(2.f * x);
  return 1.f - 2.f / (e + 1.f);
}

// relaxed agent-scope (sc1, LLC-coherent) primitives
__device__ __forceinline__ u64 ld8_llc(const u64* p) {
  return __hip_atomic_load(p, __ATOMIC_RELAXED, __HIP_MEMORY_SCOPE_AGENT);
}
__device__ __forceinline__ void st8_llc(u64* p, u64 v) {
  __hip_atomic_store(p, v, __ATOMIC_RELAXED, __HIP_MEMORY_SCOPE_AGENT);
}
__device__ __forceinline__ short8 ld16_llc(const u16* p) {
  const u64* q = (const u64*)p;
  u64 lo = ld8_llc(q), hi = ld8_llc(q + 1);
  union { u64 v[2]; short8 s; } u;
  u.v[0] = lo; u.v[1] = hi;
  return u.s;
}
__device__ __forceinline__ void st2_llc(u16* p, u16 v) {
  __hip_atomic_store(p, v, __ATOMIC_RELAXED, __HIP_MEMORY_SCOPE_AGENT);
}
__device__ __forceinline__ void st4_llc(u32* p, u32 v) {
  __hip_atomic_store(p, v, __ATOMIC_RELAXED, __HIP_MEMORY_SCOPE_AGENT);
}
__device__ __forceinline__ u32 ld4_llc(const u32* p) {
  return __hip_atomic_load(p, __ATOMIC_RELAXED, __HIP_MEMORY_SCOPE_AGENT);
}
// poll 32 packed u32 flags (one 128B line); lane i checks dword i&31
__device__ __forceinline__ void poll_sc1(const u32* base, int lane, u32 tgt) {
  const u32* pf = base + (lane & 31);
  for (;;) {
    u32 v = ld4_llc(pf);
    if (__all((int)(v >= tgt))) break;
    __builtin_amdgcn_s_sleep(1);
  }
  asm volatile("" ::: "memory");
}

__device__ __forceinline__ short8 cvt8(const float* src) {
  float4 lo = *(const float4*)src;
  float4 hi = *(const float4*)(src + 4);
  short8 fr;
  fr[0] = (short)f2bf(lo.x); fr[1] = (short)f2bf(lo.y);
  fr[2] = (short)f2bf(lo.z); fr[3] = (short)f2bf(lo.w);
  fr[4] = (short)f2bf(hi.x); fr[5] = (short)f2bf(hi.y);
  fr[6] = (short)f2bf(hi.z); fr[7] = (short)f2bf(hi.w);
  return fr;
}

// ---- embedding gather into MFMA-B fragment layout (bf16), R7 layout ----
__global__ void gather_x0(const int* __restrict__ in_t, const float* __restrict__ emb,
                          u16* __restrict__ x0) {
  int gid = blockIdx.x * 256 + threadIdx.x;
  int c = gid >> 6, lane = gid & 63;
  int t = c >> 6, rem = c & 63;
  int kt = rem >> 2, nt = rem & 3;
  int b = nt * 16 + (lane & 15);
  int k0 = kt * 32 + ((lane >> 4) * 8);
  int row = in_t[b * T_LEN + t];
  *(short8*)(x0 + (size_t)c * CHUNK_U16 + lane * 8) =
      cvt8(emb + (size_t)row * 512 + k0);
}

// ---- persistent recurrent kernel, tag-embedded h exchange ----
// 128 blocks x 512 threads (8 waves). bid: g=bid&3 (layer=g>>1, sb=g&1),
// u=bid>>2 (0..31). Unit: h [16u,16u+16) (64 gate-rows, m=4*h_local+gate) x
// samples [32sb,32sb+32). Waves 0-3: x-side, wave w covers kt [4w,4w+4).
// Waves 4-7: h-side over tagged eff-K=1024 (32 tagged-kt), wave covers 8.
// h qword-pair Qp=4*ktg+q covers real h 4Qp..4Qp+3; each u64 =
// {c(2j),c(2j+1),tag u32}; tag==t+1 published at end of step t.
__global__ __launch_bounds__(512, 1) void lstm_persist(
    const float* __restrict__ wx, const float* __restrict__ bx,
    const float* __restrict__ wh, const float* __restrict__ bh,
    const u16* __restrict__ x0, u16* __restrict__ y0,
    u16* __restrict__ hd, float* __restrict__ pool, u32* __restrict__ yflg) {
  __shared__ float part[8][64][32];   // [wave][gate-row][sample]  = 64KB

  const int tid = threadIdx.x;
  const int w = tid >> 6, lane = tid & 63;
  const int q = lane >> 4, col = lane & 15;
  const int bid = blockIdx.x;
  const int g = bid & 3;
  const int layer = g >> 1, sb = g & 1;
  const int u = bid >> 2;          // 0..31
  const bool xside = (w < 4);

  // ---- weight fragments: shared af[4][8] = 128 VGPRs ----
  short8 af[4][8];
  {
    const int gt_a = col & 3, hsub = col >> 2;
#pragma unroll
    for (int mt = 0; mt < 4; ++mt) {
      const int h_out = u * 16 + mt * 4 + hsub;
      if (xside) {
        const float* wrow = wx + ((size_t)(layer * 4 + gt_a) * 512 + h_out) * 512;
#pragma unroll
        for (int ks = 0; ks < 4; ++ks)
          af[mt][ks] = cvt8(wrow + (w * 4 + ks) * 32 + q * 8);
      } else {
        const float* wrow = wh + ((size_t)(layer * 4 + gt_a) * 512 + h_out) * 512;
        const int e = w - 4;
#pragma unroll
        for (int ks = 0; ks < 8; ++ks) {
          const int ktg = e * 8 + ks;
          const int hb = 16 * ktg + 4 * q;   // real h base of (ktg, q) octet
          short8 fr;
          fr[0] = (short)f2bf(wrow[hb + 0]);
          fr[1] = (short)f2bf(wrow[hb + 1]);
          fr[2] = 0; fr[3] = 0;              // tag slots: zero weight
          fr[4] = (short)f2bf(wrow[hb + 2]);
          fr[5] = (short)f2bf(wrow[hb + 3]);
          fr[6] = 0; fr[7] = 0;
          af[mt][ks] = fr;
        }
      }
    }
  }

  // epilogue ownership: (h_g = 16u + hl, sample n); wave w owns h-pair {2w,2w+1}
  const int hl = tid >> 5, n = tid & 31;
  const int h_g = u * 16 + hl;
  float bias[4];
#pragma unroll
  for (int r = 0; r < 4; ++r)
    bias[r] = bx[(layer * 4 + r) * 512 + h_g] + bh[(layer * 4 + r) * 512 + h_g];
  const size_t offY = ((size_t)((h_g >> 5) * 4 + sb * 2 + (n >> 4)) * 64 +
                       (n & 15) + 16 * ((h_g >> 3) & 3)) * 8 + (h_g & 7);
  // tagged u64 index: Qp = 4u + (w>>1), half = w&1 (lanes<32 store)
  const size_t hoff = ((size_t)(4 * u + (w >> 1)) * 32 + n) * 2 + (w & 1);

  const u16* xbase = layer ? y0 : x0;
  u64* hdl = (u64*)hd + (size_t)g * 2 * HSLOT_U64;
  u32* yf_own = yflg + sb * 32 + u;
  const u32* yf_grp = yflg + sb * 32;

  float cst = 0.f, opool = 0.f;

  for (int t = 0; t < T_LEN; ++t) {
    f32x4 acc[4][2] = {};
    if (xside) {
      if (layer == 1) poll_sc1(yf_grp, lane, (u32)(t + 1));
      const u16* xs = xbase + (size_t)t * XSTEP_U16;
#pragma unroll
      for (int ks = 0; ks < 4; ++ks) {
        const int ktl = w * 4 + ks;
        const u16* p = xs + ((size_t)(ktl * 4 + 2 * sb) * 64 + lane) * 8;
        short8 f0, f1;
        if (layer == 0) {
          f0 = *(const short8*)p;
          f1 = *(const short8*)(p + CHUNK_U16);
        } else {
          f0 = ld16_llc(p);
          f1 = ld16_llc(p + CHUNK_U16);
        }
#pragma unroll
        for (int mt = 0; mt < 4; ++mt) {
          acc[mt][0] = __builtin_amdgcn_mfma_f32_16x16x32_bf16(af[mt][ks], f0,
                                                               acc[mt][0], 0, 0, 0);
          acc[mt][1] = __builtin_amdgcn_mfma_f32_16x16x32_bf16(af[mt][ks], f1,
                                                               acc[mt][1], 0, 0, 0);
        }
      }
    } else {
      // ---- h-side: tagged retry loads; detect and data are ONE round ----
      const int e = w - 4;
      const u64* hs = hdl + (size_t)(t & 1) * HSLOT_U64;
      const u32 tagv = (u32)t;
#pragma unroll
      for (int c = 0; c < 2; ++c) {
        u64 d0[4], d1[4], d2[4], d3[4];   // [ks4]: ntl0 {lo,hi}, ntl1 {lo,hi}
        for (;;) {
#pragma unroll
          for (int ks4 = 0; ks4 < 4; ++ks4) {
            const int ktg = e * 8 + c * 4 + ks4;
            const u64* p0 = hs + ((size_t)((4 * ktg + q) * 32 + col)) * 2;
            const u64* p1 = hs + ((size_t)((4 * ktg + q) * 32 + 16 + col)) * 2;
            d0[ks4] = ld8_llc(p0); d1[ks4] = ld8_llc(p0 + 1);
            d2[ks4] = ld8_llc(p1); d3[ks4] = ld8_llc(p1 + 1);
          }
          int ok = 1;
#pragma unroll
          for (int ks4 = 0; ks4 < 4; ++ks4)
            ok &= (int)(((u32)(d0[ks4] >> 32) == tagv) &
                        ((u32)(d1[ks4] >> 32) == tagv) &
                        ((u32)(d2[ks4] >> 32) == tagv) &
                        ((u32)(d3[ks4] >> 32) == tagv));
          if (__all(ok)) break;
          __builtin_amdgcn_s_sleep(1);
        }
#pragma unroll
        for (int ks4 = 0; ks4 < 4; ++ks4) {
          union { u64 v[2]; short8 s; } ua, ub;
          ua.v[0] = d0[ks4]; ua.v[1] = d1[ks4];
          ub.v[0] = d2[ks4]; ub.v[1] = d3[ks4];
#pragma unroll
          for (int mt = 0; mt < 4; ++mt) {
            acc[mt][0] = __builtin_amdgcn_mfma_f32_16x16x32_bf16(
                af[mt][c * 4 + ks4], ua.s, acc[mt][0], 0, 0, 0);
            acc[mt][1] = __builtin_amdgcn_mfma_f32_16x16x32_bf16(
                af[mt][c * 4 + ks4], ub.s, acc[mt][1], 0, 0, 0);
          }
        }
      }
    }
    // partials -> LDS (C/D: col=lane&15 is sample, row = 4q + r within tile)
#pragma unroll
    for (int mt = 0; mt < 4; ++mt)
#pragma unroll
      for (int ntl = 0; ntl < 2; ++ntl)
#pragma unroll
        for (int r = 0; r < 4; ++r)
          part[w][mt * 16 + q * 4 + r][ntl * 16 + col] = acc[mt][ntl][r];
    __syncthreads();   // b1: partials ready

    if (layer == 0) {
      // deferred y certification: last step's stores are long acked -> instant
      asm volatile("s_waitcnt vmcnt(0)" ::: "memory");
      __syncthreads();                   // b_cert
      if (tid == 1) st4_llc(yf_own, (u32)t);   // certifies y(0..t-1)
    }

    // ---- epilogue: 8-wave reduce + gates ----
    float v[4];
#pragma unroll
    for (int gt = 0; gt < 4; ++gt) {
      float s = 0.f;
#pragma unroll
      for (int ww = 0; ww < 8; ++ww) s += part[ww][4 * hl + gt][n];
      v[gt] = s + bias[gt];
    }
    const float ig = sigf(v[0]);
    const float fg = sigf(v[1]);
    const float gg = tanhfast(v[2]);
    const float og = sigf(v[3]);
    const float cn = fg * cst + ig * gg;   // c input = prev h_new (unpack bug)
    const float hn = og * tanhfast(cn);
    cst = hn;
    const float pcn = __shfl_xor(cn, 32, 64);  // partner h's c_new
    {
      u64* hdst = hdl + (size_t)((t + 1) & 1) * HSLOT_U64;
      if (lane < 32) {   // one tagged u64 per h-pair: {c_even, c_odd, tag t+1}
        u64 val = (u64)(u16)f2bf(cn) | ((u64)(u16)f2bf(pcn) << 16) |
                  ((u64)(u32)(t + 1) << 32);
        st8_llc(hdst + hoff, val);       // fire-and-forget (bug: c_new is h-input)
      }
    }
    if (layer == 0) {
      st2_llc(y0 + (size_t)t * XSTEP_U16 + offY, f2bf(og));  // o -> L1 input
    } else {
      opool += og;
    }
    __syncthreads();   // b2: part[] fully read
  }

  if (layer == 0) {
    // FINAL y certification (R13's missing line -> deadlock at t=255)
    asm volatile("s_waitcnt vmcnt(0)" ::: "memory");
    __syncthreads();
    if (tid == 1) st4_llc(yf_own, (u32)T_LEN);   // certifies y(0..255)
  } else {
    pool[(size_t)h_g * 64 + sb * 32 + n] = opool;
  }
}

// ---- final pooled @ wo.T + bo -> sigmoid ----
__global__ void finalize_k(const float* __restrict__ pool, const float* __restrict__ wo,
                           const float* __restrict__ bo, float* __restrict__ out) {
  const int b = threadIdx.x;
  float s = 0.f;
  for (int h = 0; h < 512; ++h) s += pool[h * 64 + b] * wo[h];
  out[b] = sigf(s * (1.f / 256.f) + bo[0]);
}

extern "C" void kernel_launch(void* const* d_in, const int* in_sizes, int n_in,
                              void* d_out, int out_size, void* d_ws, size_t ws_size,
                              hipStream_t stream) {
  const int* in_t = (const int*)d_in[0];
  const float* emb = (const float*)d_in[1];
  const float* wx = (const float*)d_in[2];
  const float* bx = (const float*)d_in[3];
  const float* wh = (const float*)d_in[4];
  const float* bh = (const float*)d_in[5];
  const float* wo = (const float*)d_in[6];
  const float* bo = (const float*)d_in[7];
  float* out = (float*)d_out;
  char* ws = (char*)d_ws;
  u16* x0 = (u16*)(ws + OFF_X0);
  u16* y0 = (u16*)(ws + OFF_Y0);
  u16* hd = (u16*)(ws + OFF_HD);
  float* pool = (float*)(ws + OFF_POOL);
  u32* yflg = (u32*)(ws + OFF_YFLG);

  hipMemsetAsync(ws + OFF_HD, 0, SZ_HD, stream);     // h(0)=0, tags=0
  hipMemsetAsync(ws + OFF_YFLG, 0, SZ_YFLG, stream); // y flags
  gather_x0<<<4096, 256, 0, stream>>>(in_t, emb, x0);
  lstm_persist<<<128, 512, 0, stream>>>(wx, bx, wh, bh, x0, y0, hd, pool, yflg);
  finalize_k<<<1, 64, 0, stream>>>(pool, wo, bo, out);
}